// Round 6
// baseline (313.006 us; speedup 1.0000x reference)
//
#include <hip/hip_runtime.h>
#include <hip/hip_cooperative_groups.h>

namespace cg = cooperative_groups;

#define FEAT 128
#define NDATA 100000
#define KP1 16385            // NCE_K + 1
#define BSZ 64
#define PTOT (BSZ * KP1)     // 1,048,640
#define NTILE16 6250         // NDATA / 16 (exact)

typedef short short8 __attribute__((ext_vector_type(8)));
typedef float f32x4 __attribute__((ext_vector_type(4)));

__device__ __forceinline__ float wave_reduce64(float v) {
    #pragma unroll
    for (int off = 32; off >= 1; off >>= 1) v += __shfl_xor(v, off);
    return v;
}

__device__ __forceinline__ unsigned short f2bf(float f) {
    unsigned u = __float_as_uint(f);
    u += 0x7FFFu + ((u >> 16) & 1u);   // round-to-nearest-even
    return (unsigned short)(u >> 16);
}

__device__ __forceinline__ float dot4(float4 a, float4 b, float acc) {
    acc = fmaf(a.x, b.x, acc);
    acc = fmaf(a.y, b.y, acc);
    acc = fmaf(a.z, b.z, acc);
    return fmaf(a.w, b.w, acc);
}

// ---------------- embed (raw dots, no normalize): grid (8 d-tiles, 32 b-pairs)
__global__ __launch_bounds__(256) void embed_kernel(
    const float* __restrict__ fs, const float* __restrict__ ft,
    const float* __restrict__ Ws, const float* __restrict__ bs,
    const float* __restrict__ Wt, const float* __restrict__ bt,
    float* __restrict__ vraw_s, float* __restrict__ vraw_t,
    float* __restrict__ sums, float* __restrict__ out)
{
    __shared__ __align__(16) float4 FS[512];    // 2 b x 1024 f
    __shared__ __align__(16) float4 FT[1024];   // 2 b x 2048 f

    const int t  = threadIdx.x;
    const int dt = blockIdx.x;        // 0..7 -> dims dt*16 .. dt*16+15
    const int b0 = blockIdx.y * 2;    // 0..62

    if (dt == 0 && blockIdx.y == 0) {
        if (t < 2) sums[t] = 0.0f;    // replaces memsets
        if (t == 2) out[0] = 0.0f;
    }

    for (int q = t; q < 512; q += 256) {
        const int b = q >> 8, i = q & 255;
        FS[q] = ((const float4*)(fs + (size_t)(b0 + b) * 1024))[i];
    }
    for (int q = t; q < 1024; q += 256) {
        const int b = q >> 9, i = q & 511;
        FT[q] = ((const float4*)(ft + (size_t)(b0 + b) * 2048))[i];
    }
    __syncthreads();

    const int w = t >> 6, lane = t & 63;

    #pragma unroll
    for (int r = 0; r < 4; ++r) {                 // s-side: 4 dims per wave
        const int d = dt * 16 + w * 4 + r;
        const float4* wrow = (const float4*)(Ws + (size_t)d * 1024);
        float a0 = 0.0f, a1 = 0.0f;
        #pragma unroll
        for (int i = 0; i < 4; ++i) {
            const float4 wv = wrow[i * 64 + lane];
            a0 = dot4(wv, FS[i * 64 + lane], a0);
            a1 = dot4(wv, FS[256 + i * 64 + lane], a1);
        }
        a0 = wave_reduce64(a0);
        a1 = wave_reduce64(a1);
        if (lane == 0) {
            vraw_s[(size_t)b0 * 128 + d]       = a0 + bs[d];
            vraw_s[(size_t)(b0 + 1) * 128 + d] = a1 + bs[d];
        }
    }
    #pragma unroll
    for (int r = 0; r < 4; ++r) {                 // t-side
        const int d = dt * 16 + w * 4 + r;
        const float4* wrow = (const float4*)(Wt + (size_t)d * 2048);
        float a0 = 0.0f, a1 = 0.0f;
        #pragma unroll
        for (int i = 0; i < 8; ++i) {
            const float4 wv = wrow[i * 64 + lane];
            a0 = dot4(wv, FT[i * 64 + lane], a0);
            a1 = dot4(wv, FT[512 + i * 64 + lane], a1);
        }
        a0 = wave_reduce64(a0);
        a1 = wave_reduce64(a1);
        if (lane == 0) {
            vraw_t[(size_t)b0 * 128 + d]       = a0 + bt[d];
            vraw_t[(size_t)(b0 + 1) * 128 + d] = a1 + bt[d];
        }
    }
}

// ---------------- LDS-free MFMA GEMM: S[row][b] = dot(bank[row], v[b]) ------
// A-frags = v (64 rows, normalized in-wave, register-resident).
// B-frags = 16 bank rows per wave-tile, loaded straight from global.
// No LDS, no __syncthreads. grid (512, 2), block 256 = 4 independent waves.
__global__ __launch_bounds__(256) void sgemm_kernel(
    const float* __restrict__ m1, const float* __restrict__ m2,
    const float* __restrict__ vraw_s, const float* __restrict__ vraw_t,
    float* __restrict__ S1, float* __restrict__ S2)
{
    const int bank = blockIdx.y;
    const float* __restrict__ bankp = bank ? m2 : m1;
    const float* __restrict__ vp    = bank ? vraw_s : vraw_t;  // m1 x v_t, m2 x v_s
    float* __restrict__ Sp          = bank ? S2 : S1;

    const int lane = threadIdx.x & 63;
    const int n  = lane & 15;
    const int q4 = lane >> 4;

    // ---- build A-frags: load raw v, row-normalize (shfl over q4), cvt bf16
    short8 afrag[4][4];
    #pragma unroll
    for (int i = 0; i < 4; ++i) {
        float4 x[4][2];
        float ssq = 0.0f;
        #pragma unroll
        for (int kk = 0; kk < 4; ++kk) {
            const float* p = vp + (size_t)(i * 16 + n) * 128 + kk * 32 + q4 * 8;
            x[kk][0] = *(const float4*)p;
            x[kk][1] = *(const float4*)(p + 4);
            ssq = dot4(x[kk][0], x[kk][0], ssq);
            ssq = dot4(x[kk][1], x[kk][1], ssq);
        }
        ssq += __shfl_xor(ssq, 16);
        ssq += __shfl_xor(ssq, 32);
        const float inv = rsqrtf(ssq);
        #pragma unroll
        for (int kk = 0; kk < 4; ++kk) {
            short8 s;
            s[0] = (short)f2bf(x[kk][0].x * inv);
            s[1] = (short)f2bf(x[kk][0].y * inv);
            s[2] = (short)f2bf(x[kk][0].z * inv);
            s[3] = (short)f2bf(x[kk][0].w * inv);
            s[4] = (short)f2bf(x[kk][1].x * inv);
            s[5] = (short)f2bf(x[kk][1].y * inv);
            s[6] = (short)f2bf(x[kk][1].z * inv);
            s[7] = (short)f2bf(x[kk][1].w * inv);
            afrag[i][kk] = s;
        }
    }

    const int wv = blockIdx.x * 4 + (threadIdx.x >> 6);
    const int nw = gridDim.x * 4;

    float4 bx[4][2];
    int tile = wv;
    if (tile < NTILE16) {
        const float* bp = bankp + ((size_t)tile * 16 + n) * 128 + q4 * 8;
        #pragma unroll
        for (int kk = 0; kk < 4; ++kk) {
            bx[kk][0] = *(const float4*)(bp + kk * 32);
            bx[kk][1] = *(const float4*)(bp + kk * 32 + 4);
        }
    }

    while (tile < NTILE16) {
        const int nxt = tile + nw;
        float4 bx2[4][2];
        if (nxt < NTILE16) {                      // prefetch next tile
            const float* bp = bankp + ((size_t)nxt * 16 + n) * 128 + q4 * 8;
            #pragma unroll
            for (int kk = 0; kk < 4; ++kk) {
                bx2[kk][0] = *(const float4*)(bp + kk * 32);
                bx2[kk][1] = *(const float4*)(bp + kk * 32 + 4);
            }
        }

        short8 bf[4];
        #pragma unroll
        for (int kk = 0; kk < 4; ++kk) {
            short8 s;
            s[0] = (short)f2bf(bx[kk][0].x);
            s[1] = (short)f2bf(bx[kk][0].y);
            s[2] = (short)f2bf(bx[kk][0].z);
            s[3] = (short)f2bf(bx[kk][0].w);
            s[4] = (short)f2bf(bx[kk][1].x);
            s[5] = (short)f2bf(bx[kk][1].y);
            s[6] = (short)f2bf(bx[kk][1].z);
            s[7] = (short)f2bf(bx[kk][1].w);
            bf[kk] = s;
        }

        const size_t srow = (size_t)tile * 16 + n;   // D col = lane&15 = bank row
        #pragma unroll
        for (int i = 0; i < 4; ++i) {
            f32x4 acc = {0.f, 0.f, 0.f, 0.f};
            #pragma unroll
            for (int kk = 0; kk < 4; ++kk)
                acc = __builtin_amdgcn_mfma_f32_16x16x32_bf16(afrag[i][kk], bf[kk], acc, 0, 0, 0);
            *(f32x4*)(Sp + srow * 64 + i * 16 + q4 * 4) = acc;  // 4 v-idx, contiguous
        }

        #pragma unroll
        for (int kk = 0; kk < 4; ++kk) {
            bx[kk][0] = bx2[kk][0];
            bx[kk][1] = bx2[kk][1];
        }
        tile = nxt;
    }
}

// ---------------- fused gather + exp + Z + loss (cooperative) ----------------
// e-values live in registers across grid.sync(); es/et arrays eliminated.
__global__ __launch_bounds__(256) void gather_loss_kernel(
    const int* __restrict__ idx, const int* __restrict__ cidx,
    const float* __restrict__ S1, const float* __restrict__ S2,
    float* __restrict__ sums, float* __restrict__ out)
{
    const int b    = blockIdx.y;
    const int base = blockIdx.x * 2048;
    const int tid  = threadIdx.x;
    const float invT = 1.0f / 0.07f;

    int rows[8];
    #pragma unroll
    for (int j = 0; j < 8; ++j) {
        const int k = base + j * 256 + tid;
        rows[j] = (k < KP1) ? ((k == 0) ? idx[b] : cidx[(size_t)b * KP1 + k]) : -1;
    }
    float d1[8], d2[8];
    #pragma unroll
    for (int j = 0; j < 8; ++j) {
        if (rows[j] >= 0) {
            d1[j] = S1[(size_t)rows[j] * 64 + b];
            d2[j] = S2[(size_t)rows[j] * 64 + b];
        }
    }
    float e1[8], e2[8];
    float acc_s = 0.0f, acc_t = 0.0f;
    #pragma unroll
    for (int j = 0; j < 8; ++j) {
        if (rows[j] >= 0) {
            e1[j] = __expf(d1[j] * invT);   // t-side (bank m1 x v_t)
            e2[j] = __expf(d2[j] * invT);   // s-side
            acc_t += e1[j];
            acc_s += e2[j];
        }
    }

    acc_s = wave_reduce64(acc_s);
    acc_t = wave_reduce64(acc_t);
    __shared__ float ls[8];
    if ((tid & 63) == 0) {
        ls[(tid >> 6) * 2]     = acc_s;
        ls[(tid >> 6) * 2 + 1] = acc_t;
    }
    __syncthreads();
    if (tid == 0) atomicAdd(&sums[0], ls[0] + ls[2] + ls[4] + ls[6]);
    if (tid == 1) atomicAdd(&sums[1], ls[1] + ls[3] + ls[5] + ls[7]);

    cg::this_grid().sync();

    const float zn = (float)PTOT / (float)NDATA;
    const float invZs = zn / *((volatile float*)&sums[0]);
    const float invZt = zn / *((volatile float*)&sums[1]);
    const float c  = 16384.0f / 100000.0f + 1e-7f;
    const float c2 = 2.0f * -1.80886495f;     // 2*ln(16384/100000)

    float local = 0.0f;
    #pragma unroll
    for (int j = 0; j < 8; ++j) {
        if (rows[j] >= 0) {
            const float xs = e2[j] * invZs;
            const float xt = e1[j] * invZt;
            local += c2 - __logf((xs + c) * (xt + c));
            if (base + j * 256 + tid == 0)            // positive correction
                local += __logf(xs * xt) - c2;
        }
    }

    local = wave_reduce64(local);
    __shared__ float lr[4];
    if ((tid & 63) == 0) lr[tid >> 6] = local;
    __syncthreads();
    if (tid == 0) {
        const float tot = lr[0] + lr[1] + lr[2] + lr[3];
        atomicAdd(out, -tot * (1.0f / 64.0f));
    }
}

extern "C" void kernel_launch(void* const* d_in, const int* in_sizes, int n_in,
                              void* d_out, int out_size, void* d_ws, size_t ws_size,
                              hipStream_t stream) {
    const float* fs   = (const float*)d_in[0];
    const float* ft   = (const float*)d_in[1];
    const int*   idx  = (const int*)d_in[2];
    const int*   cidx = (const int*)d_in[3];
    const float* Ws   = (const float*)d_in[4];
    const float* bs   = (const float*)d_in[5];
    const float* Wt   = (const float*)d_in[6];
    const float* bt   = (const float*)d_in[7];
    const float* m1   = (const float*)d_in[8];
    const float* m2   = (const float*)d_in[9];
    float* out = (float*)d_out;

    float* ws     = (float*)d_ws;
    float* vraw_s = ws;                       // 8192
    float* vraw_t = vraw_s + 8192;            // 8192
    float* sums   = vraw_t + 8192;            // 2 (+2 pad)
    float* S1     = sums + 4;                 // NDATA x 64 (row-major)
    float* S2     = S1 + (size_t)NDATA * BSZ;

    embed_kernel<<<dim3(8, 32), dim3(256), 0, stream>>>(
        fs, ft, Ws, bs, Wt, bt, vraw_s, vraw_t, sums, out);
    sgemm_kernel<<<dim3(512, 2), dim3(256), 0, stream>>>(
        m1, m2, vraw_s, vraw_t, S1, S2);

    void* args[6];
    const int* a0 = idx; const int* a1 = cidx;
    const float* a2 = S1; const float* a3 = S2;
    float* a4 = sums; float* a5 = out;
    args[0] = &a0; args[1] = &a1; args[2] = &a2;
    args[3] = &a3; args[4] = &a4; args[5] = &a5;
    hipLaunchCooperativeKernel((void*)gather_loss_kernel,
                               dim3(9, 64), dim3(256), args, 0, stream);
}

// Round 7
// 199.458 us; speedup vs baseline: 1.5693x; 1.5693x over previous
//
#include <hip/hip_runtime.h>

#define NDATA 100000
#define KP1 16385            // NCE_K + 1
#define BSZ 64
#define PTOT (BSZ * KP1)     // 1,048,640
#define NTILES 1563          // ceil(NDATA / 64)
#define INV_T (1.0f / 0.07f)

typedef short short8 __attribute__((ext_vector_type(8)));
typedef float f32x4 __attribute__((ext_vector_type(4)));

__device__ __forceinline__ float wave_reduce64(float v) {
    #pragma unroll
    for (int off = 32; off >= 1; off >>= 1) v += __shfl_xor(v, off);
    return v;
}

__device__ __forceinline__ unsigned short f2bf(float f) {
    unsigned u = __float_as_uint(f);
    u += 0x7FFFu + ((u >> 16) & 1u);   // round-to-nearest-even
    return (unsigned short)(u >> 16);
}

__device__ __forceinline__ float dot4(float4 a, float4 b, float acc) {
    acc = fmaf(a.x, b.x, acc);
    acc = fmaf(a.y, b.y, acc);
    acc = fmaf(a.z, b.z, acc);
    return fmaf(a.w, b.w, acc);
}

// ---------------- embed: raw dots + norm^2 accumulation ----------------------
// grid (8 d-tiles, 32 b-pairs); W demand ~49 MB (L2/L3-cached).
__global__ __launch_bounds__(256) void embed_kernel(
    const float* __restrict__ fs, const float* __restrict__ ft,
    const float* __restrict__ Ws, const float* __restrict__ bs,
    const float* __restrict__ Wt, const float* __restrict__ bt,
    float* __restrict__ vraw_s, float* __restrict__ vraw_t,
    float* __restrict__ n2s, float* __restrict__ n2t)
{
    __shared__ __align__(16) float4 FS[512];    // 2 b x 1024 f
    __shared__ __align__(16) float4 FT[1024];   // 2 b x 2048 f

    const int t  = threadIdx.x;
    const int dt = blockIdx.x;        // dims dt*16 .. dt*16+15
    const int b0 = blockIdx.y * 2;

    for (int q = t; q < 512; q += 256) {
        const int b = q >> 8, i = q & 255;
        FS[q] = ((const float4*)(fs + (size_t)(b0 + b) * 1024))[i];
    }
    for (int q = t; q < 1024; q += 256) {
        const int b = q >> 9, i = q & 511;
        FT[q] = ((const float4*)(ft + (size_t)(b0 + b) * 2048))[i];
    }
    __syncthreads();

    const int w = t >> 6, lane = t & 63;
    float ps0 = 0.0f, ps1 = 0.0f, pt0 = 0.0f, pt1 = 0.0f;

    #pragma unroll
    for (int r = 0; r < 4; ++r) {                 // s-side: 4 dims per wave
        const int d = dt * 16 + w * 4 + r;
        const float4* wrow = (const float4*)(Ws + (size_t)d * 1024);
        float a0 = 0.0f, a1 = 0.0f;
        #pragma unroll
        for (int i = 0; i < 4; ++i) {
            const float4 wv = wrow[i * 64 + lane];
            a0 = dot4(wv, FS[i * 64 + lane], a0);
            a1 = dot4(wv, FS[256 + i * 64 + lane], a1);
        }
        a0 = wave_reduce64(a0) + bs[d];
        a1 = wave_reduce64(a1) + bs[d];
        ps0 = fmaf(a0, a0, ps0);
        ps1 = fmaf(a1, a1, ps1);
        if (lane == 0) {
            vraw_s[(size_t)b0 * 128 + d]       = a0;
            vraw_s[(size_t)(b0 + 1) * 128 + d] = a1;
        }
    }
    #pragma unroll
    for (int r = 0; r < 4; ++r) {                 // t-side
        const int d = dt * 16 + w * 4 + r;
        const float4* wrow = (const float4*)(Wt + (size_t)d * 2048);
        float a0 = 0.0f, a1 = 0.0f;
        #pragma unroll
        for (int i = 0; i < 8; ++i) {
            const float4 wv = wrow[i * 64 + lane];
            a0 = dot4(wv, FT[i * 64 + lane], a0);
            a1 = dot4(wv, FT[512 + i * 64 + lane], a1);
        }
        a0 = wave_reduce64(a0) + bt[d];
        a1 = wave_reduce64(a1) + bt[d];
        pt0 = fmaf(a0, a0, pt0);
        pt1 = fmaf(a1, a1, pt1);
        if (lane == 0) {
            vraw_t[(size_t)b0 * 128 + d]       = a0;
            vraw_t[(size_t)(b0 + 1) * 128 + d] = a1;
        }
    }
    if (lane == 0) {
        atomicAdd(&n2s[b0],     ps0);
        atomicAdd(&n2s[b0 + 1], ps1);
        atomicAdd(&n2t[b0],     pt0);
        atomicAdd(&n2t[b0 + 1], pt1);
    }
}

// ---------------- bf16 MFMA GEMM -> S[b][row] (transposed, raw scale) --------
// XOR-swizzled LDS (conflict-free b128), double-buffered A, 1 barrier/tile.
__device__ __forceinline__ void stage_tile(
    unsigned short* __restrict__ dst, const float* __restrict__ src,
    int row0, int t, bool clampRows)
{
    #pragma unroll
    for (int i = 0; i < 8; ++i) {
        const int q = t + i * 256;
        const int r = q >> 5, c = q & 31;
        int gr = row0 + r;
        if (clampRows && gr >= NDATA) gr = NDATA - 1;
        const float4 v = ((const float4*)(src + (size_t)gr * 128))[c];
        ushort4 u;
        u.x = f2bf(v.x); u.y = f2bf(v.y); u.z = f2bf(v.z); u.w = f2bf(v.w);
        *(ushort4*)&dst[r * 128 + (((c >> 1) ^ (r & 15)) * 8) + (c & 1) * 4] = u;
    }
}

__global__ __launch_bounds__(256) void sgemm_kernel(
    const float* __restrict__ m1, const float* __restrict__ m2,
    const float* __restrict__ vraw_s, const float* __restrict__ vraw_t,
    float* __restrict__ S1, float* __restrict__ S2)
{
    __shared__ __align__(16) unsigned short Vs[64 * 128];
    __shared__ __align__(16) unsigned short As[2][64 * 128];

    const int t = threadIdx.x;
    const int bank = blockIdx.y;
    const float* __restrict__ bankp = bank ? m2 : m1;
    const float* __restrict__ vp    = bank ? vraw_s : vraw_t;
    float* __restrict__ Sp          = bank ? S2 : S1;

    const int tile0  = blockIdx.x * 4;
    const int ntiles = min(4, NTILES - tile0);

    stage_tile(Vs, vp, 0, t, false);             // v tile (64 x 128)
    stage_tile(As[0], bankp, tile0 * 64, t, true);
    __syncthreads();

    const int lane = t & 63;
    const int m  = lane & 15;
    const int q4 = lane >> 4;
    const int m0 = (t >> 6) * 16;

    for (int it = 0; it < ntiles; ++it) {
        if (it + 1 < ntiles)
            stage_tile(As[(it + 1) & 1], bankp, (tile0 + it + 1) * 64, t, true);

        const unsigned short* A = As[it & 1];
        const int row0 = (tile0 + it) * 64;

        short8 af[4];
        #pragma unroll
        for (int kk = 0; kk < 4; ++kk)
            af[kk] = *(const short8*)&A[(m0 + m) * 128 + (((kk * 4 + q4) ^ m) * 8)];

        const int rbase = row0 + m0 + q4 * 4;
        const bool valid = (rbase < NDATA);      // 4-row chunks never straddle (NDATA%16==0)

        #pragma unroll
        for (int n0 = 0; n0 < 64; n0 += 16) {
            f32x4 acc = {0.f, 0.f, 0.f, 0.f};
            #pragma unroll
            for (int kk = 0; kk < 4; ++kk) {
                short8 bf = *(const short8*)&Vs[(n0 + m) * 128 + (((kk * 4 + q4) ^ m) * 8)];
                acc = __builtin_amdgcn_mfma_f32_16x16x32_bf16(af[kk], bf, acc, 0, 0, 0);
            }
            if (valid)
                *(f32x4*)(Sp + (size_t)(n0 + m) * NDATA + rbase) = acc;
        }
        __syncthreads();
    }
}

// ---------------- gather negatives: accumulate sum(e), sum(e^2) only ---------
// grid (64 b-major, 8 parts): k = part*2048 + j*256 + t + 1 covers k=1..16384.
__global__ __launch_bounds__(256) void gather_kernel(
    const int* __restrict__ cidx,
    const float* __restrict__ S1, const float* __restrict__ S2,
    const float* __restrict__ n2t, const float* __restrict__ n2s,
    float* __restrict__ acc)
{
    const int b = blockIdx.x, part = blockIdx.y, t = threadIdx.x;
    const float sct = INV_T * rsqrtf(n2t[b]);
    const float scs = INV_T * rsqrtf(n2s[b]);
    const float* __restrict__ S1b = S1 + (size_t)b * NDATA;
    const float* __restrict__ S2b = S2 + (size_t)b * NDATA;
    const int kbase = part * 2048 + 1;

    int rows[8];
    #pragma unroll
    for (int j = 0; j < 8; ++j)
        rows[j] = cidx[(size_t)b * KP1 + kbase + j * 256 + t];

    float v1[8], v2[8];
    #pragma unroll
    for (int j = 0; j < 8; ++j) {
        v1[j] = S1b[rows[j]];
        v2[j] = S2b[rows[j]];
    }

    float seT = 0.f, se2T = 0.f, seS = 0.f, se2S = 0.f;
    #pragma unroll
    for (int j = 0; j < 8; ++j) {
        const float e1 = __expf(v1[j] * sct);
        const float e2 = __expf(v2[j] * scs);
        seT += e1; se2T = fmaf(e1, e1, se2T);
        seS += e2; se2S = fmaf(e2, e2, se2S);
    }

    seT = wave_reduce64(seT);  se2T = wave_reduce64(se2T);
    seS = wave_reduce64(seS);  se2S = wave_reduce64(se2S);

    __shared__ float red[4][4];
    if ((t & 63) == 0) {
        const int w = t >> 6;
        red[w][0] = seT; red[w][1] = se2T; red[w][2] = seS; red[w][3] = se2S;
    }
    __syncthreads();
    if (t < 4)
        atomicAdd(&acc[t], red[0][t] + red[1][t] + red[2][t] + red[3][t]);
}

// ---------------- final: positives exact + closed-form negatives -------------
// Negatives: sum log(mPn/(x+c)) = (P-B)ln(mPn/c) - Su + Su2/2,
// Su = se_neg*invZ/c, Su2 = se2_neg*invZ^2/c^2 (u<=0.03 -> error <1e-3).
__global__ __launch_bounds__(64) void final_kernel(
    const int* __restrict__ idx,
    const float* __restrict__ S1, const float* __restrict__ S2,
    const float* __restrict__ n2t, const float* __restrict__ n2s,
    const float* __restrict__ acc, float* __restrict__ out)
{
    const int b = threadIdx.x;                 // 64 threads, one wave
    const float c = 0.16384f + 1e-7f;
    const int row = idx[b];

    const float e1p = __expf(S1[(size_t)b * NDATA + row] * INV_T * rsqrtf(n2t[b]));
    const float e2p = __expf(S2[(size_t)b * NDATA + row] * INV_T * rsqrtf(n2s[b]));

    const float pseT = wave_reduce64(e1p);
    const float pseS = wave_reduce64(e2p);

    const float seT_neg = acc[0], se2T_neg = acc[1];
    const float seS_neg = acc[2], se2S_neg = acc[3];

    const float zn = (float)PTOT / (float)NDATA;
    const float invZt = zn / (seT_neg + pseT);   // Z-sum includes positives
    const float invZs = zn / (seS_neg + pseS);

    const float PB = (float)(PTOT - BSZ);        // 1,048,576
    const float LOG_MPN_C = -6.1035156e-7f;      // ln(mPn / (mPn + 1e-7))
    const float ic = 1.0f / c;

    const float negT = PB * LOG_MPN_C
                     - seT_neg * invZt * ic
                     + 0.5f * se2T_neg * invZt * invZt * ic * ic;
    const float negS = PB * LOG_MPN_C
                     - seS_neg * invZs * ic
                     + 0.5f * se2S_neg * invZs * invZs * ic * ic;

    const float x0t = e1p * invZt, x0s = e2p * invZs;
    float pos = __logf(x0t / (x0t + c)) + __logf(x0s / (x0s + c));
    pos = wave_reduce64(pos);

    if (b == 0) out[0] = -(negT + negS + pos) * (1.0f / 64.0f);
}

extern "C" void kernel_launch(void* const* d_in, const int* in_sizes, int n_in,
                              void* d_out, int out_size, void* d_ws, size_t ws_size,
                              hipStream_t stream) {
    const float* fs   = (const float*)d_in[0];
    const float* ft   = (const float*)d_in[1];
    const int*   idx  = (const int*)d_in[2];
    const int*   cidx = (const int*)d_in[3];
    const float* Ws   = (const float*)d_in[4];
    const float* bs   = (const float*)d_in[5];
    const float* Wt   = (const float*)d_in[6];
    const float* bt   = (const float*)d_in[7];
    const float* m1   = (const float*)d_in[8];
    const float* m2   = (const float*)d_in[9];
    float* out = (float*)d_out;

    float* ws     = (float*)d_ws;
    float* n2t    = ws;                       // 64
    float* n2s    = ws + 64;                  // 64
    float* acc    = ws + 128;                 // 4 (+12 pad)
    float* vraw_s = ws + 144;                 // 8192
    float* vraw_t = vraw_s + 8192;            // 8192
    float* S1     = vraw_t + 8192;            // 64 x NDATA  [b][row]
    float* S2     = S1 + (size_t)BSZ * NDATA;

    hipMemsetAsync(ws, 0, 144 * sizeof(float), stream);   // n2t, n2s, acc

    embed_kernel<<<dim3(8, 32), dim3(256), 0, stream>>>(
        fs, ft, Ws, bs, Wt, bt, vraw_s, vraw_t, n2s, n2t);
    sgemm_kernel<<<dim3(391, 2), dim3(256), 0, stream>>>(
        m1, m2, vraw_s, vraw_t, S1, S2);
    gather_kernel<<<dim3(64, 8), dim3(256), 0, stream>>>(
        cidx, S1, S2, n2t, n2s, acc);
    final_kernel<<<dim3(1), dim3(64), 0, stream>>>(
        idx, S1, S2, n2t, n2s, acc, out);
}